// Round 6
// baseline (226.563 us; speedup 1.0000x reference)
//
#include <hip/hip_runtime.h>
#include <math.h>

// ---------------------------------------------------------------------------
// TwoSimplicialAttention, MI355X. Structure exploit: mask kills attention for
// all s < 2016; only last 32 rows/batch (64 rows) carry attention. Everything
// else is out = LayerNorm(x).
//
// R8: two dispatches, D2 geometry fixed (R7 profile: attn_wo 85us, FETCH 44MB
// from 8x-partial x 8x-mb redundant staging).
//  D1 = proj partials (4 k-splits now, 4x4 register-tiled, 256 blocks)
//       + LN of 4032 non-window rows (448 blocks) + counter zero.
//  D2 = grid (h=16, b=2, colhalf=2), 512 threads. Each block stages its
//       (h,b) K/Kp/V/Q ONCE (summing 4 partials -> ~6MB total fetch),
//       computes all 32 query rows (4 m per wave), Z stays in LDS, applies
//       Wo[h*64:(h+1)*64, ch*512:+512] -> Dp[h] partial (unique writer).
//       Split-K last-block (cnt[b] -> 32) sums 16 head partials + window LN.
// ---------------------------------------------------------------------------

#define XS 68   // attn LDS pad
#define WS 68   // gemm LDS stride

// ===== ws layout (floats); harness ws is ~256 MB ====
#define YP_STR   262144                    // one Y partial: [64][4096]
#define NKS_P    4                         // proj k-splits
#define DP_OFF   (NKS_P * YP_STR)          // 1048576: Dp[16][64][1024]
#define DP_STR   65536
#define CNT_OFF  (DP_OFF + 16 * DP_STR)    // 2097152: 2 ints

// ---------------------------------------------------------------------------
// LayerNorm of one row (no delta), one wave per row.
__device__ __forceinline__ void ln_row(
    const float4* __restrict__ x4, const float4* __restrict__ g4,
    const float4* __restrict__ b4, float4* __restrict__ out4,
    int row, int lane) {
  float4 v[4];
  #pragma unroll
  for (int i = 0; i < 4; i++) v[i] = x4[row * 256 + i * 64 + lane];
  float sum = 0.f, ss = 0.f;
  #pragma unroll
  for (int i = 0; i < 4; i++) {
    sum += v[i].x + v[i].y + v[i].z + v[i].w;
    ss  += v[i].x * v[i].x + v[i].y * v[i].y + v[i].z * v[i].z + v[i].w * v[i].w;
  }
  #pragma unroll
  for (int off = 1; off < 64; off <<= 1) {
    sum += __shfl_xor(sum, off);
    ss  += __shfl_xor(ss, off);
  }
  float mu   = sum * (1.f / 1024.f);
  float rstd = rsqrtf(ss * (1.f / 1024.f) - mu * mu + 1e-5f);
  #pragma unroll
  for (int i = 0; i < 4; i++) {
    float4 g  = g4[i * 64 + lane];
    float4 be = b4[i * 64 + lane];
    float4 o;
    o.x = (v[i].x - mu) * rstd * g.x + be.x;
    o.y = (v[i].y - mu) * rstd * g.y + be.y;
    o.z = (v[i].z - mu) * rstd * g.z + be.z;
    o.w = (v[i].w - mu) * rstd * g.w + be.w;
    out4[row * 256 + i * 64 + lane] = o;
  }
}

// ---- D1: proj partials + non-window LayerNorm + counter zero --------------
// bid < 256: Y partials[4][64][4096] = x_win @ [W_Q|W_K|W_Kp|W_V]
//   (64 colblocks of 64 cols) x (4 ksplits of 256 k); 4x4 register tile.
// bid >= 256: 448 blocks x 4 waves grid-stride LayerNorm over 4032 rows.
__global__ __launch_bounds__(256, 4) void proj_ln_kernel(
    const float* __restrict__ x,
    const float* __restrict__ Wq, const float* __restrict__ Wk,
    const float* __restrict__ Wkp, const float* __restrict__ Wv,
    const float* __restrict__ gam, const float* __restrict__ bet,
    float* __restrict__ Y, float* __restrict__ out, int* __restrict__ cnt) {
  __shared__ float xs[64 * WS];      // [kk][row]
  __shared__ float wl[64 * WS];      // [kk][col]
  const int tid = threadIdx.x;
  const int bid = blockIdx.x;

  if (bid < 256) {
    const int cb   = bid & 63;                    // colblock over 4096 cols
    const int ks   = bid >> 6;                    // 0..3
    const int col0 = cb * 64;
    const int z    = cb >> 4;                     // which W matrix
    const int colz = col0 & 1023;
    const float* __restrict__ W =
        (z == 0) ? Wq : ((z == 1) ? Wk : ((z == 2) ? Wkp : Wv));
    const int tc = tid & 15, tr = tid >> 4;       // 16x16 thread grid

    float acc[4][4];
    #pragma unroll
    for (int i = 0; i < 4; i++)
      #pragma unroll
      for (int j = 0; j < 4; j++) acc[i][j] = 0.f;

    for (int cc = 0; cc < 4; cc++) {              // 4 chunks of 64 k
      const int kb = ks * 256 + cc * 64;
      #pragma unroll
      for (int i = 0; i < 4; i++) {
        int e = i * 256 + tid;
        int r = e >> 4, q = e & 15;
        int b = r >> 5, t = r & 31;
        float4 v = *(const float4*)(x + ((b * 2048 + 2016 + t) * 1024 + kb + q * 4));
        xs[(q * 4 + 0) * WS + r] = v.x;
        xs[(q * 4 + 1) * WS + r] = v.y;
        xs[(q * 4 + 2) * WS + r] = v.z;
        xs[(q * 4 + 3) * WS + r] = v.w;
        float4 w = *(const float4*)(W + (size_t)(kb + r) * 1024 + colz + q * 4);
        *(float4*)(wl + r * WS + q * 4) = w;
      }
      __syncthreads();

      #pragma unroll 8
      for (int kk = 0; kk < 64; kk++) {
        float4 xv = *(const float4*)(xs + kk * WS + tr * 4);
        float4 wv = *(const float4*)(wl + kk * WS + tc * 4);
        acc[0][0] = fmaf(xv.x, wv.x, acc[0][0]);
        acc[0][1] = fmaf(xv.x, wv.y, acc[0][1]);
        acc[0][2] = fmaf(xv.x, wv.z, acc[0][2]);
        acc[0][3] = fmaf(xv.x, wv.w, acc[0][3]);
        acc[1][0] = fmaf(xv.y, wv.x, acc[1][0]);
        acc[1][1] = fmaf(xv.y, wv.y, acc[1][1]);
        acc[1][2] = fmaf(xv.y, wv.z, acc[1][2]);
        acc[1][3] = fmaf(xv.y, wv.w, acc[1][3]);
        acc[2][0] = fmaf(xv.z, wv.x, acc[2][0]);
        acc[2][1] = fmaf(xv.z, wv.y, acc[2][1]);
        acc[2][2] = fmaf(xv.z, wv.z, acc[2][2]);
        acc[2][3] = fmaf(xv.z, wv.w, acc[2][3]);
        acc[3][0] = fmaf(xv.w, wv.x, acc[3][0]);
        acc[3][1] = fmaf(xv.w, wv.y, acc[3][1]);
        acc[3][2] = fmaf(xv.w, wv.z, acc[3][2]);
        acc[3][3] = fmaf(xv.w, wv.w, acc[3][3]);
      }
      __syncthreads();
    }

    float* __restrict__ Yo = Y + ks * YP_STR + col0;
    #pragma unroll
    for (int i = 0; i < 4; i++) {
      float4 o = make_float4(acc[i][0], acc[i][1], acc[i][2], acc[i][3]);
      *(float4*)(Yo + (tr * 4 + i) * 4096 + tc * 4) = o;
    }
  } else {
    if (bid == 256 && tid < 2) cnt[tid] = 0;      // zero group counters
    const int wave = tid >> 6, lane = tid & 63;
    const int gw = (bid - 256) * 4 + wave;        // 1792 LN waves
    const float4* x4 = (const float4*)x;
    const float4* g4 = (const float4*)gam;
    const float4* b4 = (const float4*)bet;
    float4* out4 = (float4*)out;
    for (int idx = gw; idx < 4032; idx += 1792) {
      int row = (idx < 2016) ? idx : idx + 32;
      ln_row(x4, g4, b4, out4, row, lane);
    }
  }
}

// ---- D2: attention(all 32 rows) + wo(col-half) + last-block window-LN -----
// grid dim3(16,2,2): h=blockIdx.x, b=blockIdx.y, ch=blockIdx.z. 512 threads.
__global__ __launch_bounds__(512) void attn_wo_kernel(
    const float* __restrict__ Y, const float* __restrict__ Wo,
    const float* __restrict__ x, const float* __restrict__ gam,
    const float* __restrict__ bet, float* __restrict__ Dp,
    int* __restrict__ cnt, float* __restrict__ out) {
  __shared__ float Qs[32 * XS], Kn[32 * XS], Kp[32 * XS], Vs[32 * XS];
  __shared__ float Pt[8][32 * 33];
  __shared__ float Zs[32 * 68];
  __shared__ int done_flag;
  const int tid = threadIdx.x;
  const int wave = tid >> 6, lane = tid & 63;
  const int h = blockIdx.x, b = blockIdx.y, ch = blockIdx.z;

  // stage Q/K/Kp/V for (h,b), summing 4 ksplit partials. 2048 = 4*512 slots.
  #pragma unroll
  for (int i = 0; i < 4; i++) {
    int e = i * 512 + tid;
    int row = e >> 6, d = e & 63;
    int src = (b * 32 + row) * 4096 + h * 64 + d;
    float qq = 0.f, kn = 0.f, kp = 0.f, vv = 0.f;
    #pragma unroll
    for (int p = 0; p < NKS_P; p++) {
      const float* Yp = Y + p * YP_STR + src;
      qq += Yp[0]; kn += Yp[1024]; kp += Yp[2048]; vv += Yp[3072];
    }
    Qs[row * XS + d] = qq;
    Kn[row * XS + d] = kn; Kp[row * XS + d] = kp; Vs[row * XS + d] = vv;
  }
  __syncthreads();

  // l2-normalize Q, K, Kp rows (8 waves x 4 rows)
  for (int rr = 0; rr < 4; rr++) {
    int row = wave * 4 + rr;
    float qv = Qs[row * XS + lane];
    float q2 = qv * qv;
    #pragma unroll
    for (int off = 1; off < 64; off <<= 1) q2 += __shfl_xor(q2, off);
    Qs[row * XS + lane] = qv * (1.f / (sqrtf(q2) + 1e-7f));
    float kv = Kn[row * XS + lane];
    float s2 = kv * kv;
    #pragma unroll
    for (int off = 1; off < 64; off <<= 1) s2 += __shfl_xor(s2, off);
    Kn[row * XS + lane] = kv * (1.f / (sqrtf(s2) + 1e-7f));
    float pv = Kp[row * XS + lane];
    float p2 = pv * pv;
    #pragma unroll
    for (int off = 1; off < 64; off <<= 1) p2 += __shfl_xor(p2, off);
    Kp[row * XS + lane] = pv * (1.f / (sqrtf(p2) + 1e-7f));
  }
  __syncthreads();

  // attention: wave handles m = mm*8 + wave, mm = 0..3  (32 q-rows total)
  const int lj = lane >> 3, lk = lane & 7;
  float vreg[32];
  #pragma unroll
  for (int k = 0; k < 32; k++) vreg[k] = Vs[k * XS + lane];
  float* ptw = Pt[wave];

  for (int mm = 0; mm < 4; mm++) {
    const int m = mm * 8 + wave;
    const float* qw = Qs + m * XS;

    float acc[4][4];
    #pragma unroll
    for (int a = 0; a < 4; a++)
      #pragma unroll
      for (int c = 0; c < 4; c++) acc[a][c] = 0.f;

    for (int dq = 0; dq < 16; dq++) {
      float4 q4 = *(const float4*)(qw + dq * 4);
      float4 t4[4], kp4[4];
      #pragma unroll
      for (int tj = 0; tj < 4; tj++) {
        float4 kv = *(const float4*)(Kn + (lj * 4 + tj) * XS + dq * 4);
        t4[tj].x = q4.x * kv.x; t4[tj].y = q4.y * kv.y;
        t4[tj].z = q4.z * kv.z; t4[tj].w = q4.w * kv.w;
      }
      #pragma unroll
      for (int tk = 0; tk < 4; tk++)
        kp4[tk] = *(const float4*)(Kp + (lk * 4 + tk) * XS + dq * 4);
      #pragma unroll
      for (int tj = 0; tj < 4; tj++)
        #pragma unroll
        for (int tk = 0; tk < 4; tk++)
          acc[tj][tk] += t4[tj].x * kp4[tk].x + t4[tj].y * kp4[tk].y
                       + t4[tj].z * kp4[tk].z + t4[tj].w * kp4[tk].w;
    }

    float amax = -1e30f;
    #pragma unroll
    for (int tj = 0; tj < 4; tj++)
      #pragma unroll
      for (int tk = 0; tk < 4; tk++) {
        int j = lj * 4 + tj, k = lk * 4 + tk;
        if (j <= m && k <= m) amax = fmaxf(amax, acc[tj][tk] * 0.125f);
      }
    #pragma unroll
    for (int off = 1; off < 64; off <<= 1) amax = fmaxf(amax, __shfl_xor(amax, off));

    float lsum = 0.f;
    #pragma unroll
    for (int tj = 0; tj < 4; tj++)
      #pragma unroll
      for (int tk = 0; tk < 4; tk++) {
        int j = lj * 4 + tj, k = lk * 4 + tk;
        float e = 0.f;
        if (j <= m && k <= m) e = __expf(acc[tj][tk] * 0.125f - amax);
        lsum += e;
        ptw[k * 33 + j] = e;
      }
    #pragma unroll
    for (int off = 1; off < 64; off <<= 1) lsum += __shfl_xor(lsum, off);
    float inv = 1.f / lsum;
    __builtin_amdgcn_wave_barrier();

    float zacc = 0.f;
    for (int k = 0; k <= m; k++) {
      float g = 0.f;
      #pragma unroll
      for (int j = 0; j < 32; j++) g += ptw[k * 33 + j] * vreg[j];
      zacc += g * vreg[k];
    }
    Zs[m * 68 + lane] = zacc * inv;
    __builtin_amdgcn_wave_barrier();
  }
  __syncthreads();

  // ---- wo: Dp[h][b*32..+31][ch*512..+511] = Zs(32x64) @ Wo_h(64x512) -----
  // thread owns col quad q (128 quads per half) and 8-row group rb.
  {
    const int q  = tid & 127;
    const int rb = (tid >> 7) * 8;                 // 0,8,16,24
    const float* __restrict__ WoS =
        Wo + (size_t)h * 65536 + ch * 512 + q * 4;
    float4 acc[8];
    #pragma unroll
    for (int rr = 0; rr < 8; rr++) acc[rr] = make_float4(0.f, 0.f, 0.f, 0.f);
    #pragma unroll 8
    for (int k = 0; k < 64; k++) {
      float4 wv = *(const float4*)(WoS + (size_t)k * 1024);
      #pragma unroll
      for (int rr = 0; rr < 8; rr++) {
        float zz = Zs[(rb + rr) * 68 + k];         // LDS broadcast
        acc[rr].x = fmaf(zz, wv.x, acc[rr].x);
        acc[rr].y = fmaf(zz, wv.y, acc[rr].y);
        acc[rr].z = fmaf(zz, wv.z, acc[rr].z);
        acc[rr].w = fmaf(zz, wv.w, acc[rr].w);
      }
    }
    float* __restrict__ D = Dp + h * DP_STR + ch * 512 + q * 4;
    #pragma unroll
    for (int rr = 0; rr < 8; rr++)
      *(float4*)(D + (size_t)(b * 32 + rb + rr) * 1024) = acc[rr];
  }

  // ---- split-K last-block: 32nd block of batch b does the window LN -------
  __threadfence();
  __syncthreads();
  if (tid == 0) {
    int old = atomicAdd(cnt + b, 1);
    done_flag = (old == 31) ? 1 : 0;
  }
  __syncthreads();
  if (!done_flag) return;
  __threadfence();

  const float4* x4  = (const float4*)x;
  const float4* dp4 = (const float4*)Dp;
  const float4* g4  = (const float4*)gam;
  const float4* b4  = (const float4*)bet;
  float4* out4 = (float4*)out;

  for (int rr = 0; rr < 4; rr++) {
    const int rl  = wave * 4 + rr;                 // 0..31
    const int wr  = b * 32 + rl;
    const int row = b * 2048 + 2016 + rl;
    float4 v[4];
    #pragma unroll
    for (int i = 0; i < 4; i++) v[i] = x4[row * 256 + i * 64 + lane];
    #pragma unroll
    for (int p = 0; p < 16; p++) {
      #pragma unroll
      for (int i = 0; i < 4; i++) {
        float4 d = dp4[p * 16384 + wr * 256 + i * 64 + lane];
        v[i].x += d.x; v[i].y += d.y; v[i].z += d.z; v[i].w += d.w;
      }
    }
    float sum = 0.f, ss = 0.f;
    #pragma unroll
    for (int i = 0; i < 4; i++) {
      sum += v[i].x + v[i].y + v[i].z + v[i].w;
      ss  += v[i].x * v[i].x + v[i].y * v[i].y + v[i].z * v[i].z + v[i].w * v[i].w;
    }
    #pragma unroll
    for (int off = 1; off < 64; off <<= 1) {
      sum += __shfl_xor(sum, off);
      ss  += __shfl_xor(ss, off);
    }
    float mu   = sum * (1.f / 1024.f);
    float rstd = rsqrtf(ss * (1.f / 1024.f) - mu * mu + 1e-5f);
    #pragma unroll
    for (int i = 0; i < 4; i++) {
      float4 g  = g4[i * 64 + lane];
      float4 be = b4[i * 64 + lane];
      float4 o;
      o.x = (v[i].x - mu) * rstd * g.x + be.x;
      o.y = (v[i].y - mu) * rstd * g.y + be.y;
      o.z = (v[i].z - mu) * rstd * g.z + be.z;
      o.w = (v[i].w - mu) * rstd * g.w + be.w;
      out4[row * 256 + i * 64 + lane] = o;
    }
  }
}

// ---------------------------------------------------------------------------
extern "C" void kernel_launch(void* const* d_in, const int* in_sizes, int n_in,
                              void* d_out, int out_size, void* d_ws, size_t ws_size,
                              hipStream_t stream) {
  const float* x   = (const float*)d_in[0];
  const float* Wq  = (const float*)d_in[1];
  const float* Wk  = (const float*)d_in[2];
  const float* Wv  = (const float*)d_in[3];  // NB: dict order, W_V before W_Kp
  const float* Wkp = (const float*)d_in[4];
  const float* Wo  = (const float*)d_in[5];
  const float* gam = (const float*)d_in[6];
  const float* bet = (const float*)d_in[7];
  float* out = (float*)d_out;
  float* ws  = (float*)d_ws;   // needs ~8.4 MB (harness provides ~256 MB)
  int*   cnt = (int*)(ws + CNT_OFF);

  hipLaunchKernelGGL(proj_ln_kernel, dim3(256 + 448), dim3(256), 0, stream,
                     x, Wq, Wk, Wkp, Wv, gam, bet, ws, out, cnt);
  hipLaunchKernelGGL(attn_wo_kernel, dim3(16, 2, 2), dim3(512), 0, stream,
                     ws, Wo, x, gam, bet, ws + DP_OFF, cnt, out);
}

// Round 7
// 151.764 us; speedup vs baseline: 1.4929x; 1.4929x over previous
//
#include <hip/hip_runtime.h>
#include <math.h>

// ---------------------------------------------------------------------------
// TwoSimplicialAttention, MI355X. Structure exploit: mask kills attention for
// all s < 2016; only last 32 rows/batch (64 rows) carry attention. Everything
// else is out = LayerNorm(x).
//
// R9: parallelism-first 3-dispatch pipeline (R8 post-mortem: 64-block fusion
// was latency-bound at 4% occupancy; fetch volume was never the limit).
//  D1 = proj partials (4 ksplits, 4x4 register tile, 256 blocks)
//       + LN of 4032 non-window rows (448 blocks) + zero 16 counters.
//  D2 = reduce_norm (1024 blocks): Yn = sum of 4 partials, with l2-norm
//       applied ONCE to Q/K/Kp rows (wave per (row,head,matrix), coalesced).
//  D3 = attn (256 blocks (mb,h,b), compact normalized staging, 1 m/wave)
//       + fused per-head Wo partial + per-(mb,b) last-block window LN.
// ---------------------------------------------------------------------------

#define XS 68   // attn LDS pad
#define WS 68   // gemm LDS stride

// ===== ws layout (floats); harness ws is ~256 MB ====
#define YP_STR   262144                    // one Y partial: [64][4096]
#define NKS_P    4                         // proj k-splits
#define YN_OFF   (NKS_P * YP_STR)          // 1048576: compact Y [64][4096]
#define DP_OFF   (YN_OFF + 262144)         // 1310720: Dp[16][64][1024]
#define DP_STR   65536
#define CNT_OFF  (DP_OFF + 16 * DP_STR)    // 2359296: 16 ints

// ---------------------------------------------------------------------------
// LayerNorm of one row (no delta), one wave per row.
__device__ __forceinline__ void ln_row(
    const float4* __restrict__ x4, const float4* __restrict__ g4,
    const float4* __restrict__ b4, float4* __restrict__ out4,
    int row, int lane) {
  float4 v[4];
  #pragma unroll
  for (int i = 0; i < 4; i++) v[i] = x4[row * 256 + i * 64 + lane];
  float sum = 0.f, ss = 0.f;
  #pragma unroll
  for (int i = 0; i < 4; i++) {
    sum += v[i].x + v[i].y + v[i].z + v[i].w;
    ss  += v[i].x * v[i].x + v[i].y * v[i].y + v[i].z * v[i].z + v[i].w * v[i].w;
  }
  #pragma unroll
  for (int off = 1; off < 64; off <<= 1) {
    sum += __shfl_xor(sum, off);
    ss  += __shfl_xor(ss, off);
  }
  float mu   = sum * (1.f / 1024.f);
  float rstd = rsqrtf(ss * (1.f / 1024.f) - mu * mu + 1e-5f);
  #pragma unroll
  for (int i = 0; i < 4; i++) {
    float4 g  = g4[i * 64 + lane];
    float4 be = b4[i * 64 + lane];
    float4 o;
    o.x = (v[i].x - mu) * rstd * g.x + be.x;
    o.y = (v[i].y - mu) * rstd * g.y + be.y;
    o.z = (v[i].z - mu) * rstd * g.z + be.z;
    o.w = (v[i].w - mu) * rstd * g.w + be.w;
    out4[row * 256 + i * 64 + lane] = o;
  }
}

// ---- D1: proj partials + non-window LayerNorm + counter zero --------------
__global__ __launch_bounds__(256, 4) void proj_ln_kernel(
    const float* __restrict__ x,
    const float* __restrict__ Wq, const float* __restrict__ Wk,
    const float* __restrict__ Wkp, const float* __restrict__ Wv,
    const float* __restrict__ gam, const float* __restrict__ bet,
    float* __restrict__ Y, float* __restrict__ out, int* __restrict__ cnt) {
  __shared__ float xs[64 * WS];      // [kk][row]
  __shared__ float wl[64 * WS];      // [kk][col]
  const int tid = threadIdx.x;
  const int bid = blockIdx.x;

  if (bid < 256) {
    const int cb   = bid & 63;                    // colblock over 4096 cols
    const int ks   = bid >> 6;                    // 0..3
    const int col0 = cb * 64;
    const int z    = cb >> 4;                     // which W matrix
    const int colz = col0 & 1023;
    const float* __restrict__ W =
        (z == 0) ? Wq : ((z == 1) ? Wk : ((z == 2) ? Wkp : Wv));
    const int tc = tid & 15, tr = tid >> 4;       // 16x16 thread grid

    float acc[4][4];
    #pragma unroll
    for (int i = 0; i < 4; i++)
      #pragma unroll
      for (int j = 0; j < 4; j++) acc[i][j] = 0.f;

    for (int cc = 0; cc < 4; cc++) {              // 4 chunks of 64 k
      const int kb = ks * 256 + cc * 64;
      #pragma unroll
      for (int i = 0; i < 4; i++) {
        int e = i * 256 + tid;
        int r = e >> 4, q = e & 15;
        int b = r >> 5, t = r & 31;
        float4 v = *(const float4*)(x + ((b * 2048 + 2016 + t) * 1024 + kb + q * 4));
        xs[(q * 4 + 0) * WS + r] = v.x;
        xs[(q * 4 + 1) * WS + r] = v.y;
        xs[(q * 4 + 2) * WS + r] = v.z;
        xs[(q * 4 + 3) * WS + r] = v.w;
        float4 w = *(const float4*)(W + (size_t)(kb + r) * 1024 + colz + q * 4);
        *(float4*)(wl + r * WS + q * 4) = w;
      }
      __syncthreads();

      #pragma unroll 8
      for (int kk = 0; kk < 64; kk++) {
        float4 xv = *(const float4*)(xs + kk * WS + tr * 4);
        float4 wv = *(const float4*)(wl + kk * WS + tc * 4);
        acc[0][0] = fmaf(xv.x, wv.x, acc[0][0]);
        acc[0][1] = fmaf(xv.x, wv.y, acc[0][1]);
        acc[0][2] = fmaf(xv.x, wv.z, acc[0][2]);
        acc[0][3] = fmaf(xv.x, wv.w, acc[0][3]);
        acc[1][0] = fmaf(xv.y, wv.x, acc[1][0]);
        acc[1][1] = fmaf(xv.y, wv.y, acc[1][1]);
        acc[1][2] = fmaf(xv.y, wv.z, acc[1][2]);
        acc[1][3] = fmaf(xv.y, wv.w, acc[1][3]);
        acc[2][0] = fmaf(xv.z, wv.x, acc[2][0]);
        acc[2][1] = fmaf(xv.z, wv.y, acc[2][1]);
        acc[2][2] = fmaf(xv.z, wv.z, acc[2][2]);
        acc[2][3] = fmaf(xv.z, wv.w, acc[2][3]);
        acc[3][0] = fmaf(xv.w, wv.x, acc[3][0]);
        acc[3][1] = fmaf(xv.w, wv.y, acc[3][1]);
        acc[3][2] = fmaf(xv.w, wv.z, acc[3][2]);
        acc[3][3] = fmaf(xv.w, wv.w, acc[3][3]);
      }
      __syncthreads();
    }

    float* __restrict__ Yo = Y + ks * YP_STR + col0;
    #pragma unroll
    for (int i = 0; i < 4; i++) {
      float4 o = make_float4(acc[i][0], acc[i][1], acc[i][2], acc[i][3]);
      *(float4*)(Yo + (tr * 4 + i) * 4096 + tc * 4) = o;
    }
  } else {
    if (bid == 256 && tid < 16) cnt[tid] = 0;     // zero group counters
    const int wave = tid >> 6, lane = tid & 63;
    const int gw = (bid - 256) * 4 + wave;        // 1792 LN waves
    const float4* x4 = (const float4*)x;
    const float4* g4 = (const float4*)gam;
    const float4* b4 = (const float4*)bet;
    float4* out4 = (float4*)out;
    for (int idx = gw; idx < 4032; idx += 1792) {
      int row = (idx < 2016) ? idx : idx + 32;
      ln_row(x4, g4, b4, out4, row, lane);
    }
  }
}

// ---- D2: reduce 4 Y partials -> compact Yn, l2-normalize Q/K/Kp once ------
// 1024 blocks x 4 waves; wave task = (row 0..63, head 0..15, matrix 0..3).
__global__ __launch_bounds__(256, 8) void reduce_norm_kernel(
    const float* __restrict__ Yp, float* __restrict__ Yn) {
  const int tid  = threadIdx.x;
  const int wave = tid >> 6, lane = tid & 63;
  const int task = blockIdx.x * 4 + wave;          // 0..4095
  const int r    = task & 63;
  const int h    = (task >> 6) & 15;
  const int arr  = task >> 10;                     // 0:Q 1:K 2:Kp 3:V
  const int off  = r * 4096 + arr * 1024 + h * 64 + lane;

  float v = 0.f;
  #pragma unroll
  for (int p = 0; p < NKS_P; p++) v += Yp[p * YP_STR + off];

  if (arr < 3) {                                   // l2-normalize over head dim
    float s2 = v * v;
    #pragma unroll
    for (int o = 1; o < 64; o <<= 1) s2 += __shfl_xor(s2, o);
    v *= (1.f / (sqrtf(s2) + 1e-7f));
  }
  Yn[off] = v;
}

// ---- D3: attention + per-head Wo partial + last-block window-LN -----------
// grid dim3(8,16,2): mb, h, b. 256 threads, wave owns m = mb*4 + wave.
__global__ __launch_bounds__(256) void attn_wo_kernel(
    const float* __restrict__ Yn, const float* __restrict__ Wo,
    const float* __restrict__ x, const float* __restrict__ gam,
    const float* __restrict__ bet, float* __restrict__ Dp,
    int* __restrict__ cnt, float* __restrict__ out) {
  __shared__ float Kn[32 * XS], Kp[32 * XS], Vs[32 * XS];
  __shared__ float Pt[4][32 * 33];
  __shared__ float qs[4][64];
  __shared__ float Zs[4][64];
  __shared__ int done_flag;
  const int tid = threadIdx.x;
  const int wave = tid >> 6, lane = tid & 63;
  const int mb = blockIdx.x, h = blockIdx.y, b = blockIdx.z;

  // stage normalized K/Kp/V: 1536 float4, 6 per thread, fully coalesced
  #pragma unroll
  for (int i = 0; i < 6; i++) {
    int e = i * 256 + tid;
    int a = e >> 9;                  // 0:K 1:Kp 2:V
    int rem = e & 511;
    int row = rem >> 4, q = rem & 15;
    float4 v = *(const float4*)(Yn + (b * 32 + row) * 4096 + (a + 1) * 1024 + h * 64 + q * 4);
    float* dst = (a == 0) ? Kn : ((a == 1) ? Kp : Vs);
    *(float4*)(dst + row * XS + q * 4) = v;
  }
  __syncthreads();

  const int m = mb * 4 + wave;
  const int r = b * 32 + m;

  float q = Yn[r * 4096 + h * 64 + lane];          // already normalized
  qs[wave][lane] = q;
  __builtin_amdgcn_wave_barrier();

  const int lj = lane >> 3, lk = lane & 7;
  float acc[4][4];
  #pragma unroll
  for (int a = 0; a < 4; a++)
    #pragma unroll
    for (int c = 0; c < 4; c++) acc[a][c] = 0.f;

  const float* qw = qs[wave];
  for (int dq = 0; dq < 16; dq++) {
    float4 q4 = *(const float4*)(qw + dq * 4);
    float4 t4[4], kp4[4];
    #pragma unroll
    for (int tj = 0; tj < 4; tj++) {
      float4 kv = *(const float4*)(Kn + (lj * 4 + tj) * XS + dq * 4);
      t4[tj].x = q4.x * kv.x; t4[tj].y = q4.y * kv.y;
      t4[tj].z = q4.z * kv.z; t4[tj].w = q4.w * kv.w;
    }
    #pragma unroll
    for (int tk = 0; tk < 4; tk++)
      kp4[tk] = *(const float4*)(Kp + (lk * 4 + tk) * XS + dq * 4);
    #pragma unroll
    for (int tj = 0; tj < 4; tj++)
      #pragma unroll
      for (int tk = 0; tk < 4; tk++)
        acc[tj][tk] += t4[tj].x * kp4[tk].x + t4[tj].y * kp4[tk].y
                     + t4[tj].z * kp4[tk].z + t4[tj].w * kp4[tk].w;
  }

  float amax = -1e30f;
  #pragma unroll
  for (int tj = 0; tj < 4; tj++)
    #pragma unroll
    for (int tk = 0; tk < 4; tk++) {
      int j = lj * 4 + tj, k = lk * 4 + tk;
      if (j <= m && k <= m) amax = fmaxf(amax, acc[tj][tk] * 0.125f);
    }
  #pragma unroll
  for (int off = 1; off < 64; off <<= 1) amax = fmaxf(amax, __shfl_xor(amax, off));

  float lsum = 0.f;
  float* ptw = Pt[wave];
  #pragma unroll
  for (int tj = 0; tj < 4; tj++)
    #pragma unroll
    for (int tk = 0; tk < 4; tk++) {
      int j = lj * 4 + tj, k = lk * 4 + tk;
      float e = 0.f;
      if (j <= m && k <= m) e = __expf(acc[tj][tk] * 0.125f - amax);
      lsum += e;
      ptw[k * 33 + j] = e;
    }
  #pragma unroll
  for (int off = 1; off < 64; off <<= 1) lsum += __shfl_xor(lsum, off);
  float inv = 1.f / lsum;
  __builtin_amdgcn_wave_barrier();

  float vreg[32];
  #pragma unroll
  for (int k = 0; k < 32; k++) vreg[k] = Vs[k * XS + lane];
  float zacc = 0.f;
  for (int k = 0; k <= m; k++) {
    float g = 0.f;
    #pragma unroll
    for (int j = 0; j < 32; j++) g += ptw[k * 33 + j] * vreg[j];
    zacc += g * vreg[k];
  }
  Zs[wave][lane] = zacc * inv;     // Z slice stays in LDS
  __syncthreads();

  // ---- wo: Dp[h][r0..r0+3][:] = Zs(4x64) @ Wo[h*64:(h+1)*64, :] ----------
  float wacc[4][4];
  #pragma unroll
  for (int i = 0; i < 4; i++)
    #pragma unroll
    for (int j = 0; j < 4; j++) wacc[i][j] = 0.f;

  const float* __restrict__ WoS = Wo + (size_t)h * 65536 + tid * 4;
  #pragma unroll 4
  for (int k = 0; k < 64; k++) {
    float4 wv = *(const float4*)(WoS + (size_t)k * 1024);
    #pragma unroll
    for (int rr = 0; rr < 4; rr++) {
      float zz = Zs[rr][k];                       // LDS broadcast
      wacc[rr][0] = fmaf(zz, wv.x, wacc[rr][0]);
      wacc[rr][1] = fmaf(zz, wv.y, wacc[rr][1]);
      wacc[rr][2] = fmaf(zz, wv.z, wacc[rr][2]);
      wacc[rr][3] = fmaf(zz, wv.w, wacc[rr][3]);
    }
  }
  const int r0 = b * 32 + mb * 4;
  float* __restrict__ D = Dp + h * DP_STR;
  #pragma unroll
  for (int rr = 0; rr < 4; rr++) {
    float4 o = make_float4(wacc[rr][0], wacc[rr][1], wacc[rr][2], wacc[rr][3]);
    *(float4*)(D + (size_t)(r0 + rr) * 1024 + tid * 4) = o;
  }

  // ---- split-K last-block: 16th block of group (mb,b) does the window LN --
  __threadfence();
  __syncthreads();
  if (tid == 0) {
    int old = atomicAdd(cnt + (b * 8 + mb), 1);
    done_flag = (old == 15) ? 1 : 0;
  }
  __syncthreads();
  if (!done_flag) return;
  __threadfence();

  const int wr  = r0 + wave;                       // window row index 0..63
  const int row = b * 2048 + 2016 + mb * 4 + wave; // global row
  const float4* x4  = (const float4*)x;
  const float4* dp4 = (const float4*)Dp;
  const float4* g4  = (const float4*)gam;
  const float4* b4  = (const float4*)bet;
  float4* out4 = (float4*)out;

  float4 v[4];
  #pragma unroll
  for (int i = 0; i < 4; i++) v[i] = x4[row * 256 + i * 64 + lane];
  #pragma unroll
  for (int p = 0; p < 16; p++) {
    #pragma unroll
    for (int i = 0; i < 4; i++) {
      float4 d = dp4[p * 16384 + wr * 256 + i * 64 + lane];
      v[i].x += d.x; v[i].y += d.y; v[i].z += d.z; v[i].w += d.w;
    }
  }
  float sum = 0.f, ss = 0.f;
  #pragma unroll
  for (int i = 0; i < 4; i++) {
    sum += v[i].x + v[i].y + v[i].z + v[i].w;
    ss  += v[i].x * v[i].x + v[i].y * v[i].y + v[i].z * v[i].z + v[i].w * v[i].w;
  }
  #pragma unroll
  for (int off = 1; off < 64; off <<= 1) {
    sum += __shfl_xor(sum, off);
    ss  += __shfl_xor(ss, off);
  }
  float mu   = sum * (1.f / 1024.f);
  float rstd = rsqrtf(ss * (1.f / 1024.f) - mu * mu + 1e-5f);
  #pragma unroll
  for (int i = 0; i < 4; i++) {
    float4 g  = g4[i * 64 + lane];
    float4 be = b4[i * 64 + lane];
    float4 o;
    o.x = (v[i].x - mu) * rstd * g.x + be.x;
    o.y = (v[i].y - mu) * rstd * g.y + be.y;
    o.z = (v[i].z - mu) * rstd * g.z + be.z;
    o.w = (v[i].w - mu) * rstd * g.w + be.w;
    out4[row * 256 + i * 64 + lane] = o;
  }
}

// ---------------------------------------------------------------------------
extern "C" void kernel_launch(void* const* d_in, const int* in_sizes, int n_in,
                              void* d_out, int out_size, void* d_ws, size_t ws_size,
                              hipStream_t stream) {
  const float* x   = (const float*)d_in[0];
  const float* Wq  = (const float*)d_in[1];
  const float* Wk  = (const float*)d_in[2];
  const float* Wv  = (const float*)d_in[3];  // NB: dict order, W_V before W_Kp
  const float* Wkp = (const float*)d_in[4];
  const float* Wo  = (const float*)d_in[5];
  const float* gam = (const float*)d_in[6];
  const float* bet = (const float*)d_in[7];
  float* out = (float*)d_out;
  float* ws  = (float*)d_ws;   // needs ~9.5 MB (harness provides ~256 MB)
  int*   cnt = (int*)(ws + CNT_OFF);

  hipLaunchKernelGGL(proj_ln_kernel, dim3(256 + 448), dim3(256), 0, stream,
                     x, Wq, Wk, Wkp, Wv, gam, bet, ws, out, cnt);
  hipLaunchKernelGGL(reduce_norm_kernel, dim3(1024), dim3(256), 0, stream,
                     ws, ws + YN_OFF);
  hipLaunchKernelGGL(attn_wo_kernel, dim3(8, 16, 2), dim3(256), 0, stream,
                     ws + YN_OFF, Wo, x, gam, bet, ws + DP_OFF, cnt, out);
}